// Round 1
// baseline (625.628 us; speedup 1.0000x reference)
//
#include <hip/hip_runtime.h>
#include <stdint.h>

typedef __attribute__((ext_vector_type(8))) __bf16 bf16x8;
typedef __attribute__((ext_vector_type(4))) float f32x4;
typedef __attribute__((ext_vector_type(8))) unsigned short u16x8;
typedef __attribute__((ext_vector_type(4))) unsigned short u16x4;

#define N_NODES 50000
#define N_EDGES 800000
#define C_IN    256
#define HID     128
#define C_OUT   128

__device__ __forceinline__ float bf2f(unsigned short u) {
  union { unsigned int u; float f; } c; c.u = ((unsigned int)u) << 16; return c.f;
}
__device__ __forceinline__ unsigned short f2bf(float f) {
  union { float f; unsigned int u; } c; c.f = f;
  unsigned int x = c.u + 0x7FFFu + ((c.u >> 16) & 1u);  // RNE
  return (unsigned short)(x >> 16);
}

// ---- normalize edge_index (int64 OR int32 storage) -> src,dst int32 ----
__global__ void k_idx(const int* __restrict__ raw, int* __restrict__ src,
                      int* __restrict__ dst) {
  int e = blockIdx.x * 256 + threadIdx.x;
  // int64 layout => odd 32-bit slots (hi words) of first 16 entries are all 0.
  // int32 layout => those slots are random indices in [0,50000): P(all 0) ~ 0.
  bool is64 = true;
  #pragma unroll
  for (int i = 0; i < 16; ++i) is64 = is64 && (raw[2*i+1] == 0);
  if (e < N_EDGES) {
    if (is64) {
      const long long* r = (const long long*)raw;
      src[e] = (int)r[e];
      dst[e] = (int)r[N_EDGES + e];
    } else {
      src[e] = raw[e];
      dst[e] = raw[N_EDGES + e];
    }
  }
}

// ---- rearrange W (K x Ncols, f32) into MFMA B-fragments, bf16 ----
// frag[t], t = ((c*(K/32) + kk)*64 + lane)*8 + j
// supplies B[k][col], k = kk*32 + (lane>>4)*8 + j, col = c*16 + (lane&15)
__global__ void k_prep_w(const float* __restrict__ W, unsigned short* __restrict__ frag,
                         int Ncols) {
  int t = blockIdx.x * 256 + threadIdx.x;     // K fixed = 256 -> K/32 = 8
  int total = 8 * (Ncols / 16) * 64 * 8;
  if (t >= total) return;
  int j    = t & 7;
  int lane = (t >> 3) & 63;
  int kk   = (t >> 9) & 7;
  int c    = t >> 12;
  int k    = kk * 32 + (lane >> 4) * 8 + j;
  int col  = c * 16 + (lane & 15);
  frag[t] = f2bf(W[(size_t)k * Ncols + col]);
}

// ---- node GEMM: qk = x @ W_proj + b_proj -> q,k stored bf16 ----
__global__ __launch_bounds__(256) void k_node(
    const float* __restrict__ x, const unsigned short* __restrict__ wpf,
    const float* __restrict__ b_proj,
    unsigned short* __restrict__ qb, unsigned short* __restrict__ kb) {
  __shared__ unsigned short xs[64 * 264];   // 264 = 256 + 8 pad (bank spread)
  int base = blockIdx.x * 64;
  int tid = threadIdx.x;
  #pragma unroll
  for (int it = 0; it < 16; ++it) {
    int idx = it * 256 + tid;               // 4096 float4 chunks
    int row = idx >> 6;
    int c4  = idx & 63;
    float4 v = make_float4(0.f, 0.f, 0.f, 0.f);
    if (base + row < N_NODES)
      v = *(const float4*)(x + (size_t)(base + row) * C_IN + c4 * 4);
    u16x4 u = { f2bf(v.x), f2bf(v.y), f2bf(v.z), f2bf(v.w) };
    *(u16x4*)&xs[row * 264 + c4 * 4] = u;
  }
  __syncthreads();
  int lane = tid & 63, w = tid >> 6;
  f32x4 acc[16];
  #pragma unroll
  for (int c = 0; c < 16; ++c) acc[c] = (f32x4){0.f, 0.f, 0.f, 0.f};
  int arow  = w * 16 + (lane & 15);
  int koffb = (lane >> 4) * 8;
  #pragma unroll
  for (int kk = 0; kk < 8; ++kk) {
    bf16x8 a = *(const bf16x8*)&xs[arow * 264 + kk * 32 + koffb];
    #pragma unroll
    for (int c = 0; c < 16; ++c) {
      bf16x8 b = *(const bf16x8*)(wpf + (((c * 8 + kk) * 64 + lane) << 3));
      acc[c] = __builtin_amdgcn_mfma_f32_16x16x32_bf16(a, b, acc[c], 0, 0, 0);
    }
  }
  int r0   = base + w * 16 + ((lane >> 4) << 2);
  int colb = lane & 15;
  #pragma unroll
  for (int c = 0; c < 16; ++c) {
    int col = c * 16 + colb;
    float bp = b_proj[col];
    #pragma unroll
    for (int j = 0; j < 4; ++j) {
      int row = r0 + j;
      if (row < N_NODES) {
        unsigned short h = f2bf(acc[c][j] + bp);
        if (col < HID) qb[(size_t)row * HID + col] = h;
        else           kb[(size_t)row * HID + col - HID] = h;
      }
    }
  }
}

// ---- edge kernel: gather q/k, edge_attr=[q*k | q-k], @ W_o + b_o ----
__global__ __launch_bounds__(256, 4) void k_edge(
    const int* __restrict__ src, const int* __restrict__ dst,
    const unsigned short* __restrict__ qb, const unsigned short* __restrict__ kb,
    const unsigned short* __restrict__ wof, const float* __restrict__ b_o,
    float* __restrict__ out) {
  __shared__ unsigned short ea[64 * 264];
  int base = blockIdx.x * 64;               // E = 12500 * 64 exactly
  int tid = threadIdx.x;
  int e = tid >> 2, q4 = tid & 3;
  int s = src[base + e], d = dst[base + e];
  const u16x8* qrow = (const u16x8*)(qb + (size_t)s * HID);
  const u16x8* krow = (const u16x8*)(kb + (size_t)d * HID);
  #pragma unroll
  for (int i = 0; i < 4; ++i) {
    int c8 = q4 * 4 + i;                    // 16 chunks of 8 bf16 = 128 cols
    u16x8 q8 = qrow[c8];
    u16x8 k8 = krow[c8];
    u16x8 p8, m8;
    #pragma unroll
    for (int j = 0; j < 8; ++j) {
      float qf = bf2f(q8[j]), kf = bf2f(k8[j]);
      p8[j] = f2bf(qf * kf);
      m8[j] = f2bf(qf - kf);
    }
    *(u16x8*)&ea[e * 264 + c8 * 8]       = p8;   // channels [0,128)
    *(u16x8*)&ea[e * 264 + 128 + c8 * 8] = m8;   // channels [128,256)
  }
  __syncthreads();
  int lane = tid & 63, w = tid >> 6;
  f32x4 acc[8];
  #pragma unroll
  for (int c = 0; c < 8; ++c) acc[c] = (f32x4){0.f, 0.f, 0.f, 0.f};
  int arow  = w * 16 + (lane & 15);
  int koffb = (lane >> 4) * 8;
  #pragma unroll
  for (int kk = 0; kk < 8; ++kk) {
    bf16x8 a = *(const bf16x8*)&ea[arow * 264 + kk * 32 + koffb];
    #pragma unroll
    for (int c = 0; c < 8; ++c) {
      bf16x8 b = *(const bf16x8*)(wof + (((c * 8 + kk) * 64 + lane) << 3));
      acc[c] = __builtin_amdgcn_mfma_f32_16x16x32_bf16(a, b, acc[c], 0, 0, 0);
    }
  }
  int r0   = base + w * 16 + ((lane >> 4) << 2);
  int colb = lane & 15;
  #pragma unroll
  for (int c = 0; c < 8; ++c) {
    int col = c * 16 + colb;
    float bo = b_o[col];
    #pragma unroll
    for (int j = 0; j < 4; ++j) {
      out[(size_t)(r0 + j) * C_OUT + col] = acc[c][j] + bo;
    }
  }
}

extern "C" void kernel_launch(void* const* d_in, const int* in_sizes, int n_in,
                              void* d_out, int out_size, void* d_ws, size_t ws_size,
                              hipStream_t stream) {
  const float* x      = (const float*)d_in[0];
  const int*   eidx   = (const int*)d_in[1];
  const float* W_proj = (const float*)d_in[2];
  const float* b_proj = (const float*)d_in[3];
  const float* W_o    = (const float*)d_in[4];
  const float* b_o    = (const float*)d_in[5];
  float* out = (float*)d_out;

  // workspace carve-up (~32.3 MB total)
  char* ws = (char*)d_ws;
  int* src = (int*)ws;                        ws += (size_t)N_EDGES * 4;
  int* dst = (int*)ws;                        ws += (size_t)N_EDGES * 4;
  unsigned short* qb  = (unsigned short*)ws;  ws += (size_t)N_NODES * HID * 2;
  unsigned short* kb  = (unsigned short*)ws;  ws += (size_t)N_NODES * HID * 2;
  unsigned short* wof = (unsigned short*)ws;  ws += 8 * 8 * 64 * 8 * 2;
  unsigned short* wpf = (unsigned short*)ws;  ws += 16 * 8 * 64 * 8 * 2;

  k_idx<<<dim3((N_EDGES + 255) / 256), dim3(256), 0, stream>>>(eidx, src, dst);
  k_prep_w<<<dim3((8 * 8 * 64 * 8 + 255) / 256), dim3(256), 0, stream>>>(W_o, wof, C_OUT);
  k_prep_w<<<dim3((16 * 8 * 64 * 8 + 255) / 256), dim3(256), 0, stream>>>(W_proj, wpf, 256);
  k_node<<<dim3((N_NODES + 63) / 64), dim3(256), 0, stream>>>(x, wpf, b_proj, qb, kb);
  k_edge<<<dim3(N_EDGES / 64), dim3(256), 0, stream>>>(src, dst, qb, kb, wof, b_o, out);
}

// Round 2
// 600.562 us; speedup vs baseline: 1.0417x; 1.0417x over previous
//
#include <hip/hip_runtime.h>
#include <stdint.h>

typedef __attribute__((ext_vector_type(8))) __bf16 bf16x8;
typedef __attribute__((ext_vector_type(4))) float f32x4;
typedef __attribute__((ext_vector_type(8))) unsigned short u16x8;
typedef __attribute__((ext_vector_type(4))) unsigned short u16x4;

#define N_NODES 50000
#define N_EDGES 800000
#define C_IN    256
#define HID     128
#define C_OUT   128
#define NT      (N_EDGES / 64)   // 12500 edge tiles
#define NBLK_E  1024
#define EA_STRIDE 264

__device__ __forceinline__ float bf2f(unsigned short u) {
  union { unsigned int u; float f; } c; c.u = ((unsigned int)u) << 16; return c.f;
}
__device__ __forceinline__ unsigned short f2bf(float f) {
  union { float f; unsigned int u; } c; c.f = f;
  unsigned int x = c.u + 0x7FFFu + ((c.u >> 16) & 1u);  // RNE
  return (unsigned short)(x >> 16);
}

// ---- rearrange W (256 x Ncols, f32) into MFMA B-fragments, bf16 ----
// frag[t], t = ((c*8 + kk)*64 + lane)*8 + j
// supplies B[k][col], k = kk*32 + (lane>>4)*8 + j, col = c*16 + (lane&15)
__global__ void k_prep_w(const float* __restrict__ W, unsigned short* __restrict__ frag,
                         int Ncols) {
  int t = blockIdx.x * 256 + threadIdx.x;
  int total = 8 * (Ncols / 16) * 64 * 8;
  if (t >= total) return;
  int j    = t & 7;
  int lane = (t >> 3) & 63;
  int kk   = (t >> 9) & 7;
  int c    = t >> 12;
  int k    = kk * 32 + (lane >> 4) * 8 + j;
  int col  = c * 16 + (lane & 15);
  frag[t] = f2bf(W[(size_t)k * Ncols + col]);
}

// ---- node GEMM: qk = x @ W_proj + b_proj -> q,k stored bf16 ----
__global__ __launch_bounds__(256) void k_node(
    const float* __restrict__ x, const unsigned short* __restrict__ wpf,
    const float* __restrict__ b_proj,
    unsigned short* __restrict__ qb, unsigned short* __restrict__ kb) {
  __shared__ unsigned short xs[64 * EA_STRIDE];
  int base = blockIdx.x * 64;
  int tid = threadIdx.x;
  #pragma unroll
  for (int it = 0; it < 16; ++it) {
    int idx = it * 256 + tid;               // 4096 float4 chunks
    int row = idx >> 6;
    int c4  = idx & 63;
    float4 v = make_float4(0.f, 0.f, 0.f, 0.f);
    if (base + row < N_NODES)
      v = *(const float4*)(x + (size_t)(base + row) * C_IN + c4 * 4);
    u16x4 u = { f2bf(v.x), f2bf(v.y), f2bf(v.z), f2bf(v.w) };
    *(u16x4*)&xs[row * EA_STRIDE + c4 * 4] = u;
  }
  __syncthreads();
  int lane = tid & 63, w = tid >> 6;
  f32x4 acc[16];
  #pragma unroll
  for (int c = 0; c < 16; ++c) acc[c] = (f32x4){0.f, 0.f, 0.f, 0.f};
  int arow  = w * 16 + (lane & 15);
  int koffb = (lane >> 4) * 8;
  #pragma unroll
  for (int kk = 0; kk < 8; ++kk) {
    bf16x8 a = *(const bf16x8*)&xs[arow * EA_STRIDE + kk * 32 + koffb];
    #pragma unroll
    for (int c = 0; c < 16; ++c) {
      bf16x8 b = *(const bf16x8*)(wpf + (((c * 8 + kk) * 64 + lane) << 3));
      acc[c] = __builtin_amdgcn_mfma_f32_16x16x32_bf16(a, b, acc[c], 0, 0, 0);
    }
  }
  int r0   = base + w * 16 + ((lane >> 4) << 2);
  int colb = lane & 15;
  #pragma unroll
  for (int c = 0; c < 16; ++c) {
    int col = c * 16 + colb;
    float bp = b_proj[col];
    #pragma unroll
    for (int j = 0; j < 4; ++j) {
      int row = r0 + j;
      if (row < N_NODES) {
        unsigned short h = f2bf(acc[c][j] + bp);
        if (col < HID) qb[(size_t)row * HID + col] = h;
        else           kb[(size_t)row * HID + col - HID] = h;
      }
    }
  }
}

// ---- edge kernel: fused idx decode + gather + [q*k | q-k] + @W_o + b_o ----
// Grid-stride persistent blocks. Each wave owns a 32-col output slice and
// holds its W_o fragments in registers (loaded once per block).
// Double-buffered LDS tile; next tile's gather is issued before the sync so
// HBM/L2 latency lands under the MFMA+store phase.
__global__ __launch_bounds__(256) void k_edge(
    const int* __restrict__ eraw,
    const unsigned short* __restrict__ qb, const unsigned short* __restrict__ kb,
    const unsigned short* __restrict__ wof, const float* __restrict__ b_o,
    float* __restrict__ out) {
  __shared__ unsigned short ea[2][64 * EA_STRIDE];
  const int tid   = threadIdx.x;
  const int lane  = tid & 63, w = tid >> 6;
  const int e_loc = tid >> 2, q4 = tid & 3;

  // int64 layout => hi words of first 16 entries all 0 (int32: ~impossible)
  bool is64 = true;
  #pragma unroll
  for (int i = 0; i < 16; ++i) is64 = is64 && (eraw[2 * i + 1] == 0);
  const long long* e64 = (const long long*)eraw;

  // B fragments in registers: wave w covers output cols [w*32, w*32+32)
  bf16x8 bfr[2][8];
  #pragma unroll
  for (int ct = 0; ct < 2; ++ct)
    #pragma unroll
    for (int kk = 0; kk < 8; ++kk)
      bfr[ct][kk] = *(const bf16x8*)(wof + ((((w * 2 + ct) * 8 + kk) * 64 + lane) << 3));
  const float bo0 = b_o[w * 32 + (lane & 15)];
  const float bo1 = b_o[w * 32 + 16 + (lane & 15)];

  u16x8 qv[4], kv[4];
  int t = blockIdx.x;
  if (t < NT) {
    int ge = t * 64 + e_loc;
    int s, d;
    if (is64) { s = (int)e64[ge]; d = (int)e64[N_EDGES + ge]; }
    else      { s = eraw[ge];     d = eraw[N_EDGES + ge]; }
    const u16x8* qrow = (const u16x8*)(qb + (size_t)s * HID);
    const u16x8* krow = (const u16x8*)(kb + (size_t)d * HID);
    #pragma unroll
    for (int i = 0; i < 4; ++i) { qv[i] = qrow[q4 * 4 + i]; kv[i] = krow[q4 * 4 + i]; }
  }

  int buf = 0;
  for (; t < NT; t += NBLK_E) {
    unsigned short* eb = &ea[buf][0];
    // elementwise from staged registers -> LDS
    #pragma unroll
    for (int i = 0; i < 4; ++i) {
      int c8 = q4 * 4 + i;
      u16x8 p8, m8;
      #pragma unroll
      for (int j = 0; j < 8; ++j) {
        float qf = bf2f(qv[i][j]), kf = bf2f(kv[i][j]);
        p8[j] = f2bf(qf * kf);
        m8[j] = f2bf(qf - kf);
      }
      *(u16x8*)&eb[e_loc * EA_STRIDE + c8 * 8]       = p8;   // [0,128)
      *(u16x8*)&eb[e_loc * EA_STRIDE + 128 + c8 * 8] = m8;   // [128,256)
    }
    // issue next tile's gather (lands under MFMA+stores)
    int tn = t + NBLK_E;
    if (tn < NT) {
      int ge = tn * 64 + e_loc;
      int s, d;
      if (is64) { s = (int)e64[ge]; d = (int)e64[N_EDGES + ge]; }
      else      { s = eraw[ge];     d = eraw[N_EDGES + ge]; }
      const u16x8* qrow = (const u16x8*)(qb + (size_t)s * HID);
      const u16x8* krow = (const u16x8*)(kb + (size_t)d * HID);
      #pragma unroll
      for (int i = 0; i < 4; ++i) { qv[i] = qrow[q4 * 4 + i]; kv[i] = krow[q4 * 4 + i]; }
    }
    __syncthreads();
    // MFMA: 4 edge-subtiles x 2 col-subtiles, K=256
    f32x4 acc[4][2];
    #pragma unroll
    for (int et = 0; et < 4; ++et) {
      acc[et][0] = (f32x4){0.f, 0.f, 0.f, 0.f};
      acc[et][1] = (f32x4){0.f, 0.f, 0.f, 0.f};
    }
    const int arow_off = (lane & 15) * EA_STRIDE + (lane >> 4) * 8;
    #pragma unroll
    for (int kk = 0; kk < 8; ++kk) {
      #pragma unroll
      for (int et = 0; et < 4; ++et) {
        bf16x8 a = *(const bf16x8*)&eb[et * 16 * EA_STRIDE + arow_off + kk * 32];
        acc[et][0] = __builtin_amdgcn_mfma_f32_16x16x32_bf16(a, bfr[0][kk], acc[et][0], 0, 0, 0);
        acc[et][1] = __builtin_amdgcn_mfma_f32_16x16x32_bf16(a, bfr[1][kk], acc[et][1], 0, 0, 0);
      }
    }
    // store f32 out (+bias)
    #pragma unroll
    for (int et = 0; et < 4; ++et) {
      int r0 = t * 64 + et * 16 + ((lane >> 4) << 2);
      #pragma unroll
      for (int j = 0; j < 4; ++j) {
        float* op = out + (size_t)(r0 + j) * C_OUT + w * 32 + (lane & 15);
        op[0]  = acc[et][0][j] + bo0;
        op[16] = acc[et][1][j] + bo1;
      }
    }
    buf ^= 1;
  }
}

extern "C" void kernel_launch(void* const* d_in, const int* in_sizes, int n_in,
                              void* d_out, int out_size, void* d_ws, size_t ws_size,
                              hipStream_t stream) {
  const float* x      = (const float*)d_in[0];
  const int*   eidx   = (const int*)d_in[1];
  const float* W_proj = (const float*)d_in[2];
  const float* b_proj = (const float*)d_in[3];
  const float* W_o    = (const float*)d_in[4];
  const float* b_o    = (const float*)d_in[5];
  float* out = (float*)d_out;

  // workspace carve-up
  char* ws = (char*)d_ws;
  unsigned short* qb  = (unsigned short*)ws;  ws += (size_t)N_NODES * HID * 2;
  unsigned short* kb  = (unsigned short*)ws;  ws += (size_t)N_NODES * HID * 2;
  unsigned short* wof = (unsigned short*)ws;  ws += 8 * 8 * 64 * 8 * 2;
  unsigned short* wpf = (unsigned short*)ws;  ws += 16 * 8 * 64 * 8 * 2;

  k_prep_w<<<dim3((8 * 8 * 64 * 8 + 255) / 256), dim3(256), 0, stream>>>(W_o, wof, C_OUT);
  k_prep_w<<<dim3((16 * 8 * 64 * 8 + 255) / 256), dim3(256), 0, stream>>>(W_proj, wpf, 256);
  k_node<<<dim3((N_NODES + 63) / 64), dim3(256), 0, stream>>>(x, wpf, b_proj, qb, kb);
  k_edge<<<dim3(NBLK_E), dim3(256), 0, stream>>>(eidx, qb, kb, wof, b_o, out);
}